// Round 8
// baseline (203.695 us; speedup 1.0000x reference)
//
#include <hip/hip_runtime.h>

#define IN_F 256
#define OUT_F 128
#define BSH 7
#define BNODES 128          // nodes per bucket = 1<<BSH
#define MAXBUCK 1024        // supports n_nodes <= 131072
#define BIN_BLOCKS 256

typedef short bf16x8 __attribute__((ext_vector_type(8)));
typedef float f32x4 __attribute__((ext_vector_type(4)));

__device__ inline unsigned short f2bf(float x) {
    union { float f; unsigned u; } v; v.f = x;
    unsigned r = v.u + 0x7FFFu + ((v.u >> 16) & 1u);   // round-nearest-even
    return (unsigned short)(r >> 16);
}
__device__ inline float bf2f(unsigned short x) {
    union { unsigned u; float f; } v; v.u = ((unsigned)x) << 16;
    return v.f;
}

// ---------------------------------------------------------------------------
// wprep: Wt[128][256] = bf16(W^T). Also zeroes bhist.
// ---------------------------------------------------------------------------
__global__ __launch_bounds__(256) void wprep_kernel(const float* __restrict__ W,
                                                    unsigned short* __restrict__ Wt,
                                                    int* __restrict__ bhist) {
    int n = blockIdx.x;      // 0..127
    int k = threadIdx.x;     // 0..255
    Wt[n * IN_F + k] = f2bf(W[k * OUT_F + n]);
    if (threadIdx.x < 8) bhist[blockIdx.x * 8 + threadIdx.x] = 0;
}

// ---------------------------------------------------------------------------
// bin1a: per-block LDS histogram of dst buckets -> global bhist accumulate.
// ---------------------------------------------------------------------------
__global__ __launch_bounds__(256) void bin1a_kernel(const int* __restrict__ dst,
                                                    int* __restrict__ bhist,
                                                    int n_edges, int nbuck) {
    __shared__ int hist[MAXBUCK];
    const int tid = threadIdx.x;
    const int chunk = (n_edges + gridDim.x - 1) / gridDim.x;
    const int lo = blockIdx.x * chunk;
    const int hi = min(lo + chunk, n_edges);

    for (int i = tid; i < MAXBUCK; i += 256) hist[i] = 0;
    __syncthreads();
    for (int e = lo + tid; e < hi; e += 256)
        atomicAdd(&hist[dst[e] >> BSH], 1);
    __syncthreads();
    for (int i = tid; i < nbuck; i += 256) {
        int c = hist[i];
        if (c) atomicAdd(&bhist[i], c);
    }
}

// ---------------------------------------------------------------------------
// scanb: single-block exclusive scan over bucket counts -> bstart, gcur.
// ---------------------------------------------------------------------------
__global__ __launch_bounds__(1024) void scanb_kernel(const int* __restrict__ bhist,
                                                     int* __restrict__ bstart,
                                                     int* __restrict__ gcur,
                                                     int* __restrict__ rstart,
                                                     int nbuck, int n_nodes) {
    __shared__ int sh[1024];
    int tid = threadIdx.x;
    int v = (tid < nbuck) ? bhist[tid] : 0;
    sh[tid] = v;
    __syncthreads();
    #pragma unroll
    for (int off = 1; off < 1024; off <<= 1) {
        int t = (tid >= off) ? sh[tid - off] : 0;
        __syncthreads();
        sh[tid] += t;
        __syncthreads();
    }
    int ex = sh[tid] - v;
    if (tid < nbuck) { bstart[tid] = ex; gcur[tid] = ex; }
    if (tid == 1023) {
        bstart[nbuck] = sh[1023];
        rstart[n_nodes] = sh[1023];   // sentinel (== n_edges)
    }
}

// ---------------------------------------------------------------------------
// bin1b: two-pass LDS-histogram binning into bucket-grouped ebuf.
// ebuf[pos] = (src << BSH) | (dst & 127)
// ---------------------------------------------------------------------------
__global__ __launch_bounds__(256) void bin1b_kernel(const int* __restrict__ src,
                                                    const int* __restrict__ dst,
                                                    int* __restrict__ gcur,
                                                    unsigned* __restrict__ ebuf,
                                                    int n_edges, int nbuck) {
    __shared__ int hist[MAXBUCK];
    __shared__ int lbase[MAXBUCK];
    const int tid = threadIdx.x;
    const int chunk = (n_edges + gridDim.x - 1) / gridDim.x;
    const int lo = blockIdx.x * chunk;
    const int hi = min(lo + chunk, n_edges);

    for (int i = tid; i < nbuck; i += 256) hist[i] = 0;
    __syncthreads();
    for (int e = lo + tid; e < hi; e += 256)
        atomicAdd(&hist[dst[e] >> BSH], 1);
    __syncthreads();
    for (int i = tid; i < nbuck; i += 256) {
        int c = hist[i];
        lbase[i] = (c > 0) ? atomicAdd(&gcur[i], c) : 0;
        hist[i] = 0;            // reuse as local cursor
    }
    __syncthreads();
    for (int e = lo + tid; e < hi; e += 256) {
        int d = dst[e];
        int bkt = d >> BSH;
        int off = atomicAdd(&hist[bkt], 1);
        ebuf[lbase[bkt] + off] = ((unsigned)src[e] << BSH) | (unsigned)(d & (BNODES - 1));
    }
}

// ---------------------------------------------------------------------------
// bin2: one block per bucket. Per-node counts from ebuf (LDS), 128-wide scan
// -> rstart + norm, then exact per-node CSR placement. All writes bucket-local.
// ---------------------------------------------------------------------------
__global__ __launch_bounds__(256) void bin2_kernel(const unsigned* __restrict__ ebuf,
                                                   const int* __restrict__ bstart,
                                                   int* __restrict__ rstart,
                                                   float* __restrict__ norm,
                                                   int* __restrict__ eidx,
                                                   int n_nodes) {
    __shared__ int lcnt[BNODES];
    __shared__ int lex[BNODES];
    const int tid = threadIdx.x;
    const int node0 = blockIdx.x << BSH;
    const int e0 = bstart[blockIdx.x];
    const int e1 = bstart[blockIdx.x + 1];

    if (tid < BNODES) lcnt[tid] = 0;
    __syncthreads();
    for (int e = e0 + tid; e < e1; e += 256)
        atomicAdd(&lcnt[ebuf[e] & (BNODES - 1)], 1);
    __syncthreads();

    int own = (tid < BNODES) ? lcnt[tid] : 0;
    if (tid < BNODES) lex[tid] = own;
    __syncthreads();
    #pragma unroll
    for (int off = 1; off < BNODES; off <<= 1) {
        int t = (tid >= off && tid < BNODES) ? lex[tid - off] : 0;
        __syncthreads();
        if (tid < BNODES) lex[tid] += t;
        __syncthreads();
    }
    if (tid < BNODES) {
        int ex = lex[tid] - own;       // exclusive
        lex[tid] = ex;
        int g = node0 + tid;
        if (g <= n_nodes) rstart[g] = e0 + ex;
        if (g < n_nodes) {
            float d = (float)own;
            if (d < 1.0f) d = 1.0f;
            norm[g] = 1.0f / sqrtf(d);
        }
        lcnt[tid] = 0;                 // reuse as cursor
    }
    __syncthreads();

    for (int e = e0 + tid; e < e1; e += 256) {
        unsigned pk = ebuf[e];
        int dl = pk & (BNODES - 1);
        int pos = atomicAdd(&lcnt[dl], 1);
        eidx[e0 + lex[dl] + pos] = (int)(pk >> BSH);
    }
}

// ---------------------------------------------------------------------------
// gemm: h = bf16( feat @ W ). The wave's whole 16-row A footprint (16 x
// f32x4 per lane) is loaded up front and PINNED LIVE with a volatile asm
// register fence, so all 16 HBM loads are issued back-to-back (one vmcnt
// join) instead of being re-sunk into the K-loop by the scheduler.
// Success indicator: VGPR_Count jumps from 56 to ~130+.
// ---------------------------------------------------------------------------
__global__ __launch_bounds__(256) void gemm_mfma(const float* __restrict__ feat,
                                                 const unsigned short* __restrict__ Wt,
                                                 unsigned short* __restrict__ h,
                                                 int n_nodes) {
    const int wave = threadIdx.x >> 6;
    const int lane = threadIdx.x & 63;
    const int r0   = (blockIdx.x * 4 + wave) * 16;
    const int lrow = lane & 15;
    const int kgrp = (lane >> 4) * 8;

    const int row  = r0 + lrow;
    const int rowc = (row < n_nodes) ? row : (n_nodes - 1);
    const float* arow = feat + (size_t)rowc * IN_F;

    // hoist the wave's entire A footprint: 8 k-steps x 2 f32x4 per lane
    f32x4 a[16];
    #pragma unroll
    for (int k0 = 0; k0 < IN_F / 32; ++k0) {
        a[2 * k0]     = *reinterpret_cast<const f32x4*>(arow + k0 * 32 + kgrp);
        a[2 * k0 + 1] = *reinterpret_cast<const f32x4*>(arow + k0 * 32 + kgrp + 4);
    }
    // liveness fence: forces all 16 loads issued & kept in VGPRs here
    #pragma unroll
    for (int i = 0; i < 16; ++i)
        asm volatile("" : "+v"(a[i]));

    f32x4 acc[8];
    #pragma unroll
    for (int n = 0; n < 8; ++n) acc[n] = (f32x4){0.f, 0.f, 0.f, 0.f};

    #pragma unroll
    for (int k0 = 0; k0 < IN_F / 32; ++k0) {
        const f32x4 a0 = a[2 * k0];
        const f32x4 a1 = a[2 * k0 + 1];
        bf16x8 afr;
        afr[0] = (short)f2bf(a0[0]);
        afr[1] = (short)f2bf(a0[1]);
        afr[2] = (short)f2bf(a0[2]);
        afr[3] = (short)f2bf(a0[3]);
        afr[4] = (short)f2bf(a1[0]);
        afr[5] = (short)f2bf(a1[1]);
        afr[6] = (short)f2bf(a1[2]);
        afr[7] = (short)f2bf(a1[3]);
        #pragma unroll
        for (int n = 0; n < 8; ++n) {
            bf16x8 bfr = *reinterpret_cast<const bf16x8*>(
                Wt + (size_t)(n * 16 + lrow) * IN_F + k0 * 32 + kgrp);
            acc[n] = __builtin_amdgcn_mfma_f32_16x16x32_bf16(afr, bfr, acc[n], 0, 0, 0);
        }
    }

    const int orow0 = r0 + (lane >> 4) * 4;
    #pragma unroll
    for (int n = 0; n < 8; ++n) {
        #pragma unroll
        for (int j = 0; j < 4; ++j) {
            int orow = orow0 + j;
            if (orow < n_nodes)
                h[(size_t)orow * OUT_F + n * 16 + lrow] = f2bf(acc[n][j]);
        }
    }
}

// ---------------------------------------------------------------------------
// agg: one wave per dst node. Per 64-edge chunk: eidx + norm[src] loaded
// lane-parallel ONCE (coalesced), distributed via shfl; h-row gathers 4-deep.
// ---------------------------------------------------------------------------
__global__ __launch_bounds__(256) void agg_kernel(const unsigned short* __restrict__ h,
                                                  const int* __restrict__ eidx,
                                                  const int* __restrict__ rstart,
                                                  const float* __restrict__ norm,
                                                  const float* __restrict__ bias,
                                                  float* __restrict__ out,
                                                  int n_nodes) {
    const int wave = threadIdx.x >> 6;
    const int lane = threadIdx.x & 63;
    const int node = blockIdx.x * 4 + wave;
    if (node >= n_nodes) return;

    const int start = rstart[node];
    const int cnt   = rstart[node + 1] - start;

    float a0 = 0.f, a1 = 0.f;
    for (int base = 0; base < cnt; base += 64) {
        const int rem = min(64, cnt - base);
        int   ev = (lane < rem) ? eidx[start + base + lane] : 0;
        float nv = (lane < rem) ? norm[ev] : 0.f;

        int j = 0;
        for (; j + 4 <= rem; j += 4) {
            int s0 = __shfl(ev, j),     s1 = __shfl(ev, j + 1);
            int s2 = __shfl(ev, j + 2), s3 = __shfl(ev, j + 3);
            float n0 = __shfl(nv, j),     n1 = __shfl(nv, j + 1);
            float n2 = __shfl(nv, j + 2), n3 = __shfl(nv, j + 3);
            unsigned v0 = *reinterpret_cast<const unsigned*>(h + (size_t)s0 * OUT_F + lane * 2);
            unsigned v1 = *reinterpret_cast<const unsigned*>(h + (size_t)s1 * OUT_F + lane * 2);
            unsigned v2 = *reinterpret_cast<const unsigned*>(h + (size_t)s2 * OUT_F + lane * 2);
            unsigned v3 = *reinterpret_cast<const unsigned*>(h + (size_t)s3 * OUT_F + lane * 2);
            a0 += bf2f((unsigned short)(v0 & 0xffffu)) * n0;
            a1 += bf2f((unsigned short)(v0 >> 16))     * n0;
            a0 += bf2f((unsigned short)(v1 & 0xffffu)) * n1;
            a1 += bf2f((unsigned short)(v1 >> 16))     * n1;
            a0 += bf2f((unsigned short)(v2 & 0xffffu)) * n2;
            a1 += bf2f((unsigned short)(v2 >> 16))     * n2;
            a0 += bf2f((unsigned short)(v3 & 0xffffu)) * n3;
            a1 += bf2f((unsigned short)(v3 >> 16))     * n3;
        }
        for (; j < rem; ++j) {
            int   s  = __shfl(ev, j);
            float nm = __shfl(nv, j);
            unsigned v = *reinterpret_cast<const unsigned*>(h + (size_t)s * OUT_F + lane * 2);
            a0 += bf2f((unsigned short)(v & 0xffffu)) * nm;
            a1 += bf2f((unsigned short)(v >> 16))     * nm;
        }
    }

    const float nd = norm[node];
    float2 r;
    r.x = a0 * nd + bias[lane * 2];
    r.y = a1 * nd + bias[lane * 2 + 1];
    *reinterpret_cast<float2*>(out + (size_t)node * OUT_F + lane * 2) = r;
}

// ---------------------------------------------------------------------------
extern "C" void kernel_launch(void* const* d_in, const int* in_sizes, int n_in,
                              void* d_out, int out_size, void* d_ws, size_t ws_size,
                              hipStream_t stream) {
    const float* feat   = (const float*)d_in[0];
    const float* weight = (const float*)d_in[1];
    const float* bias   = (const float*)d_in[2];
    const int*   src    = (const int*)d_in[3];
    const int*   dst    = (const int*)d_in[4];
    float* out = (float*)d_out;

    const int n_nodes = in_sizes[0] / IN_F;
    const int n_edges = in_sizes[3];
    const int nbuck   = (n_nodes + BNODES - 1) >> BSH;

    char* ws = (char*)d_ws;
    size_t off = 0;
    auto alloc = [&](size_t bytes) {
        char* p = ws + off;
        off += (bytes + 15) & ~(size_t)15;
        return p;
    };
    unsigned short* h  = (unsigned short*)alloc((size_t)n_nodes * OUT_F * 2);
    float* norm        = (float*)alloc((size_t)n_nodes * 4);
    int*   rstart      = (int*)alloc(((size_t)n_nodes + 1) * 4);
    int*   bhist       = (int*)alloc(MAXBUCK * 4);
    int*   bstart      = (int*)alloc((MAXBUCK + 1) * 4);
    int*   gcur        = (int*)alloc(MAXBUCK * 4);
    unsigned short* Wt = (unsigned short*)alloc((size_t)OUT_F * IN_F * 2);
    unsigned* ebuf     = (unsigned*)alloc((size_t)n_edges * 4);
    int*   eidx        = (int*)alloc((size_t)n_edges * 4);

    wprep_kernel<<<OUT_F, IN_F, 0, stream>>>(weight, Wt, bhist);
    bin1a_kernel<<<BIN_BLOCKS, 256, 0, stream>>>(dst, bhist, n_edges, nbuck);
    scanb_kernel<<<1, 1024, 0, stream>>>(bhist, bstart, gcur, rstart, nbuck, n_nodes);
    bin1b_kernel<<<BIN_BLOCKS, 256, 0, stream>>>(src, dst, gcur, ebuf, n_edges, nbuck);
    gemm_mfma<<<(n_nodes + 63) / 64, 256, 0, stream>>>(feat, Wt, h, n_nodes);
    bin2_kernel<<<nbuck, 256, 0, stream>>>(ebuf, bstart, rstart, norm, eidx, n_nodes);
    agg_kernel<<<(n_nodes + 3) / 4, 256, 0, stream>>>(h, eidx, rstart, norm, bias, out, n_nodes);
}

// Round 9
// 160.351 us; speedup vs baseline: 1.2703x; 1.2703x over previous
//
#include <hip/hip_runtime.h>

#define IN_F 256
#define OUT_F 128
#define BSH 7
#define BNODES 128          // nodes per bucket = 1<<BSH
#define MAXBUCK 1024        // supports n_nodes <= 131072
#define BIN_BLOCKS 256

typedef short bf16x8 __attribute__((ext_vector_type(8)));
typedef float f32x4 __attribute__((ext_vector_type(4)));

__device__ inline unsigned short f2bf(float x) {
    union { float f; unsigned u; } v; v.f = x;
    unsigned r = v.u + 0x7FFFu + ((v.u >> 16) & 1u);   // round-nearest-even
    return (unsigned short)(r >> 16);
}
__device__ inline float bf2f(unsigned short x) {
    union { unsigned u; float f; } v; v.u = ((unsigned)x) << 16;
    return v.f;
}

// ---------------------------------------------------------------------------
// wprep: Wt[128][256] = bf16(W^T). Also zeroes bhist.
// ---------------------------------------------------------------------------
__global__ __launch_bounds__(256) void wprep_kernel(const float* __restrict__ W,
                                                    unsigned short* __restrict__ Wt,
                                                    int* __restrict__ bhist) {
    int n = blockIdx.x;      // 0..127
    int k = threadIdx.x;     // 0..255
    Wt[n * IN_F + k] = f2bf(W[k * OUT_F + n]);
    if (threadIdx.x < 8) bhist[blockIdx.x * 8 + threadIdx.x] = 0;
}

// ---------------------------------------------------------------------------
// bin1a: per-block LDS histogram of dst buckets -> global bhist accumulate.
// ---------------------------------------------------------------------------
__global__ __launch_bounds__(256) void bin1a_kernel(const int* __restrict__ dst,
                                                    int* __restrict__ bhist,
                                                    int n_edges, int nbuck) {
    __shared__ int hist[MAXBUCK];
    const int tid = threadIdx.x;
    const int chunk = (n_edges + gridDim.x - 1) / gridDim.x;
    const int lo = blockIdx.x * chunk;
    const int hi = min(lo + chunk, n_edges);

    for (int i = tid; i < MAXBUCK; i += 256) hist[i] = 0;
    __syncthreads();
    for (int e = lo + tid; e < hi; e += 256)
        atomicAdd(&hist[dst[e] >> BSH], 1);
    __syncthreads();
    for (int i = tid; i < nbuck; i += 256) {
        int c = hist[i];
        if (c) atomicAdd(&bhist[i], c);
    }
}

// ---------------------------------------------------------------------------
// scanb: single-block exclusive scan over bucket counts -> bstart, gcur.
// ---------------------------------------------------------------------------
__global__ __launch_bounds__(1024) void scanb_kernel(const int* __restrict__ bhist,
                                                     int* __restrict__ bstart,
                                                     int* __restrict__ gcur,
                                                     int* __restrict__ rstart,
                                                     int nbuck, int n_nodes) {
    __shared__ int sh[1024];
    int tid = threadIdx.x;
    int v = (tid < nbuck) ? bhist[tid] : 0;
    sh[tid] = v;
    __syncthreads();
    #pragma unroll
    for (int off = 1; off < 1024; off <<= 1) {
        int t = (tid >= off) ? sh[tid - off] : 0;
        __syncthreads();
        sh[tid] += t;
        __syncthreads();
    }
    int ex = sh[tid] - v;
    if (tid < nbuck) { bstart[tid] = ex; gcur[tid] = ex; }
    if (tid == 1023) {
        bstart[nbuck] = sh[1023];
        rstart[n_nodes] = sh[1023];   // sentinel (== n_edges)
    }
}

// ---------------------------------------------------------------------------
// bin1b: two-pass LDS-histogram binning into bucket-grouped ebuf.
// ebuf[pos] = (src << BSH) | (dst & 127)
// ---------------------------------------------------------------------------
__global__ __launch_bounds__(256) void bin1b_kernel(const int* __restrict__ src,
                                                    const int* __restrict__ dst,
                                                    int* __restrict__ gcur,
                                                    unsigned* __restrict__ ebuf,
                                                    int n_edges, int nbuck) {
    __shared__ int hist[MAXBUCK];
    __shared__ int lbase[MAXBUCK];
    const int tid = threadIdx.x;
    const int chunk = (n_edges + gridDim.x - 1) / gridDim.x;
    const int lo = blockIdx.x * chunk;
    const int hi = min(lo + chunk, n_edges);

    for (int i = tid; i < nbuck; i += 256) hist[i] = 0;
    __syncthreads();
    for (int e = lo + tid; e < hi; e += 256)
        atomicAdd(&hist[dst[e] >> BSH], 1);
    __syncthreads();
    for (int i = tid; i < nbuck; i += 256) {
        int c = hist[i];
        lbase[i] = (c > 0) ? atomicAdd(&gcur[i], c) : 0;
        hist[i] = 0;            // reuse as local cursor
    }
    __syncthreads();
    for (int e = lo + tid; e < hi; e += 256) {
        int d = dst[e];
        int bkt = d >> BSH;
        int off = atomicAdd(&hist[bkt], 1);
        ebuf[lbase[bkt] + off] = ((unsigned)src[e] << BSH) | (unsigned)(d & (BNODES - 1));
    }
}

// ---------------------------------------------------------------------------
// bin2: one block per bucket. Per-node counts from ebuf (LDS), 128-wide scan
// -> rstart + norm, then exact per-node CSR placement. All writes bucket-local.
// ---------------------------------------------------------------------------
__global__ __launch_bounds__(256) void bin2_kernel(const unsigned* __restrict__ ebuf,
                                                   const int* __restrict__ bstart,
                                                   int* __restrict__ rstart,
                                                   float* __restrict__ norm,
                                                   int* __restrict__ eidx,
                                                   int n_nodes) {
    __shared__ int lcnt[BNODES];
    __shared__ int lex[BNODES];
    const int tid = threadIdx.x;
    const int node0 = blockIdx.x << BSH;
    const int e0 = bstart[blockIdx.x];
    const int e1 = bstart[blockIdx.x + 1];

    if (tid < BNODES) lcnt[tid] = 0;
    __syncthreads();
    for (int e = e0 + tid; e < e1; e += 256)
        atomicAdd(&lcnt[ebuf[e] & (BNODES - 1)], 1);
    __syncthreads();

    int own = (tid < BNODES) ? lcnt[tid] : 0;
    if (tid < BNODES) lex[tid] = own;
    __syncthreads();
    #pragma unroll
    for (int off = 1; off < BNODES; off <<= 1) {
        int t = (tid >= off && tid < BNODES) ? lex[tid - off] : 0;
        __syncthreads();
        if (tid < BNODES) lex[tid] += t;
        __syncthreads();
    }
    if (tid < BNODES) {
        int ex = lex[tid] - own;       // exclusive
        lex[tid] = ex;
        int g = node0 + tid;
        if (g <= n_nodes) rstart[g] = e0 + ex;
        if (g < n_nodes) {
            float d = (float)own;
            if (d < 1.0f) d = 1.0f;
            norm[g] = 1.0f / sqrtf(d);
        }
        lcnt[tid] = 0;                 // reuse as cursor
    }
    __syncthreads();

    for (int e = e0 + tid; e < e1; e += 256) {
        unsigned pk = ebuf[e];
        int dl = pk & (BNODES - 1);
        int pos = atomicAdd(&lcnt[dl], 1);
        eidx[e0 + lex[dl] + pos] = (int)(pk >> BSH);
    }
}

// ---------------------------------------------------------------------------
// gemm: h = bf16( feat @ W ). 512 threads (8 waves x 16 rows = 128 rows/blk).
// The ENTIRE Wt (128x256 bf16 = 64 KB) is staged into LDS once per block
// with an XOR-swizzled layout (chunk16 ^= row&7: kills the 16-way bank
// conflict of the naive 512B-row layout; involution, 128B-line-preserving
// on the global side). B-fragment reads become ds_read_b128 at the LDS
// data-rate floor instead of 64 serialized ~200cy L2 round-trips per wave
// (which was the round-5..7 critical path). A footprint hoisted + pinned.
// ---------------------------------------------------------------------------
__global__ __launch_bounds__(512) void gemm_mfma(const float* __restrict__ feat,
                                                 const unsigned short* __restrict__ Wt,
                                                 unsigned short* __restrict__ h,
                                                 int n_nodes) {
    __shared__ unsigned short Bs[OUT_F * IN_F];   // 64 KB, swizzled

    const int tid  = threadIdx.x;
    const int wave = tid >> 6;
    const int lane = tid & 63;
    const int r0   = (blockIdx.x * 8 + wave) * 16;
    const int lrow = lane & 15;
    const int g    = lane >> 4;          // k-group 0..3
    const int kgrp = g * 8;

    // --- stage Wt -> LDS (swizzled): 4096 x 16B chunks, 8 per thread ---
    {
        const f32x4* srcv = reinterpret_cast<const f32x4*>(Wt);
        f32x4* dstv = reinterpret_cast<f32x4*>(Bs);
        #pragma unroll
        for (int i = 0; i < 8; ++i) {
            int c   = tid + i * 512;        // 16B-chunk index 0..4095
            int row = c >> 5;               // 0..127
            int col = c & 31;               // 16B unit within row
            dstv[c] = srcv[row * 32 + (col ^ (row & 7))];
        }
    }

    const int row  = r0 + lrow;
    const int rowc = (row < n_nodes) ? row : (n_nodes - 1);
    const float* arow = feat + (size_t)rowc * IN_F;

    // hoist the wave's entire A footprint: 8 k-steps x 2 f32x4 per lane
    f32x4 a[16];
    #pragma unroll
    for (int k0 = 0; k0 < IN_F / 32; ++k0) {
        a[2 * k0]     = *reinterpret_cast<const f32x4*>(arow + k0 * 32 + kgrp);
        a[2 * k0 + 1] = *reinterpret_cast<const f32x4*>(arow + k0 * 32 + kgrp + 4);
    }
    #pragma unroll
    for (int i = 0; i < 16; ++i)
        asm volatile("" : "+v"(a[i]));

    __syncthreads();   // Bs ready

    f32x4 acc[8];
    #pragma unroll
    for (int n = 0; n < 8; ++n) acc[n] = (f32x4){0.f, 0.f, 0.f, 0.f};

    const bf16x8* bsv = reinterpret_cast<const bf16x8*>(Bs);

    #pragma unroll
    for (int k0 = 0; k0 < IN_F / 32; ++k0) {
        const f32x4 a0 = a[2 * k0];
        const f32x4 a1 = a[2 * k0 + 1];
        bf16x8 afr;
        afr[0] = (short)f2bf(a0[0]);
        afr[1] = (short)f2bf(a0[1]);
        afr[2] = (short)f2bf(a0[2]);
        afr[3] = (short)f2bf(a0[3]);
        afr[4] = (short)f2bf(a1[0]);
        afr[5] = (short)f2bf(a1[1]);
        afr[6] = (short)f2bf(a1[2]);
        afr[7] = (short)f2bf(a1[3]);
        #pragma unroll
        for (int n = 0; n < 8; ++n) {
            const int brow = n * 16 + lrow;
            bf16x8 bfr = bsv[brow * 32 + ((k0 * 4 + g) ^ (brow & 7))];
            acc[n] = __builtin_amdgcn_mfma_f32_16x16x32_bf16(afr, bfr, acc[n], 0, 0, 0);
        }
    }

    const int orow0 = r0 + g * 4;
    #pragma unroll
    for (int n = 0; n < 8; ++n) {
        #pragma unroll
        for (int j = 0; j < 4; ++j) {
            int orow = orow0 + j;
            if (orow < n_nodes)
                h[(size_t)orow * OUT_F + n * 16 + lrow] = f2bf(acc[n][j]);
        }
    }
}

// ---------------------------------------------------------------------------
// agg: one wave per dst node. Per 64-edge chunk: eidx + norm[src] loaded
// lane-parallel ONCE (coalesced), distributed via shfl; h-row gathers 4-deep.
// ---------------------------------------------------------------------------
__global__ __launch_bounds__(256) void agg_kernel(const unsigned short* __restrict__ h,
                                                  const int* __restrict__ eidx,
                                                  const int* __restrict__ rstart,
                                                  const float* __restrict__ norm,
                                                  const float* __restrict__ bias,
                                                  float* __restrict__ out,
                                                  int n_nodes) {
    const int wave = threadIdx.x >> 6;
    const int lane = threadIdx.x & 63;
    const int node = blockIdx.x * 4 + wave;
    if (node >= n_nodes) return;

    const int start = rstart[node];
    const int cnt   = rstart[node + 1] - start;

    float a0 = 0.f, a1 = 0.f;
    for (int base = 0; base < cnt; base += 64) {
        const int rem = min(64, cnt - base);
        int   ev = (lane < rem) ? eidx[start + base + lane] : 0;
        float nv = (lane < rem) ? norm[ev] : 0.f;

        int j = 0;
        for (; j + 4 <= rem; j += 4) {
            int s0 = __shfl(ev, j),     s1 = __shfl(ev, j + 1);
            int s2 = __shfl(ev, j + 2), s3 = __shfl(ev, j + 3);
            float n0 = __shfl(nv, j),     n1 = __shfl(nv, j + 1);
            float n2 = __shfl(nv, j + 2), n3 = __shfl(nv, j + 3);
            unsigned v0 = *reinterpret_cast<const unsigned*>(h + (size_t)s0 * OUT_F + lane * 2);
            unsigned v1 = *reinterpret_cast<const unsigned*>(h + (size_t)s1 * OUT_F + lane * 2);
            unsigned v2 = *reinterpret_cast<const unsigned*>(h + (size_t)s2 * OUT_F + lane * 2);
            unsigned v3 = *reinterpret_cast<const unsigned*>(h + (size_t)s3 * OUT_F + lane * 2);
            a0 += bf2f((unsigned short)(v0 & 0xffffu)) * n0;
            a1 += bf2f((unsigned short)(v0 >> 16))     * n0;
            a0 += bf2f((unsigned short)(v1 & 0xffffu)) * n1;
            a1 += bf2f((unsigned short)(v1 >> 16))     * n1;
            a0 += bf2f((unsigned short)(v2 & 0xffffu)) * n2;
            a1 += bf2f((unsigned short)(v2 >> 16))     * n2;
            a0 += bf2f((unsigned short)(v3 & 0xffffu)) * n3;
            a1 += bf2f((unsigned short)(v3 >> 16))     * n3;
        }
        for (; j < rem; ++j) {
            int   s  = __shfl(ev, j);
            float nm = __shfl(nv, j);
            unsigned v = *reinterpret_cast<const unsigned*>(h + (size_t)s * OUT_F + lane * 2);
            a0 += bf2f((unsigned short)(v & 0xffffu)) * nm;
            a1 += bf2f((unsigned short)(v >> 16))     * nm;
        }
    }

    const float nd = norm[node];
    float2 r;
    r.x = a0 * nd + bias[lane * 2];
    r.y = a1 * nd + bias[lane * 2 + 1];
    *reinterpret_cast<float2*>(out + (size_t)node * OUT_F + lane * 2) = r;
}

// ---------------------------------------------------------------------------
extern "C" void kernel_launch(void* const* d_in, const int* in_sizes, int n_in,
                              void* d_out, int out_size, void* d_ws, size_t ws_size,
                              hipStream_t stream) {
    const float* feat   = (const float*)d_in[0];
    const float* weight = (const float*)d_in[1];
    const float* bias   = (const float*)d_in[2];
    const int*   src    = (const int*)d_in[3];
    const int*   dst    = (const int*)d_in[4];
    float* out = (float*)d_out;

    const int n_nodes = in_sizes[0] / IN_F;
    const int n_edges = in_sizes[3];
    const int nbuck   = (n_nodes + BNODES - 1) >> BSH;

    char* ws = (char*)d_ws;
    size_t off = 0;
    auto alloc = [&](size_t bytes) {
        char* p = ws + off;
        off += (bytes + 15) & ~(size_t)15;
        return p;
    };
    unsigned short* h  = (unsigned short*)alloc((size_t)n_nodes * OUT_F * 2);
    float* norm        = (float*)alloc((size_t)n_nodes * 4);
    int*   rstart      = (int*)alloc(((size_t)n_nodes + 1) * 4);
    int*   bhist       = (int*)alloc(MAXBUCK * 4);
    int*   bstart      = (int*)alloc((MAXBUCK + 1) * 4);
    int*   gcur        = (int*)alloc(MAXBUCK * 4);
    unsigned short* Wt = (unsigned short*)alloc((size_t)OUT_F * IN_F * 2);
    unsigned* ebuf     = (unsigned*)alloc((size_t)n_edges * 4);
    int*   eidx        = (int*)alloc((size_t)n_edges * 4);

    wprep_kernel<<<OUT_F, IN_F, 0, stream>>>(weight, Wt, bhist);
    bin1a_kernel<<<BIN_BLOCKS, 256, 0, stream>>>(dst, bhist, n_edges, nbuck);
    scanb_kernel<<<1, 1024, 0, stream>>>(bhist, bstart, gcur, rstart, nbuck, n_nodes);
    bin1b_kernel<<<BIN_BLOCKS, 256, 0, stream>>>(src, dst, gcur, ebuf, n_edges, nbuck);
    gemm_mfma<<<(n_nodes + 127) / 128, 512, 0, stream>>>(feat, Wt, h, n_nodes);
    bin2_kernel<<<nbuck, 256, 0, stream>>>(ebuf, bstart, rstart, norm, eidx, n_nodes);
    agg_kernel<<<(n_nodes + 3) / 4, 256, 0, stream>>>(h, eidx, rstart, norm, bias, out, n_nodes);
}

// Round 10
// 155.892 us; speedup vs baseline: 1.3066x; 1.0286x over previous
//
#include <hip/hip_runtime.h>

#define IN_F 256
#define OUT_F 128
#define BSH 7
#define BNODES 128          // nodes per bucket = 1<<BSH
#define MAXBUCK 1024        // supports n_nodes <= 131072
#define BIN1A_BLOCKS 256
#define BIN1B_BLOCKS 256

typedef short bf16x8 __attribute__((ext_vector_type(8)));
typedef float f32x4 __attribute__((ext_vector_type(4)));

__device__ inline unsigned short f2bf(float x) {
    union { float f; unsigned u; } v; v.f = x;
    unsigned r = v.u + 0x7FFFu + ((v.u >> 16) & 1u);   // round-nearest-even
    return (unsigned short)(r >> 16);
}
__device__ inline float bf2f(unsigned short x) {
    union { unsigned u; float f; } v; v.u = ((unsigned)x) << 16;
    return v.f;
}

// ---------------------------------------------------------------------------
// K1 fused: blocks [0, BIN1A_BLOCKS) = bin1a (LDS histogram of dst buckets ->
// global bhist accumulate); blocks [BIN1A_BLOCKS, +128) = wprep (Wt = bf16(W^T)).
// Independent: bin1a touches dst/bhist, wprep touches W/Wt. bhist zeroed by
// hipMemsetAsync before this dispatch.
// ---------------------------------------------------------------------------
__global__ __launch_bounds__(256) void prep_kernel(const float* __restrict__ W,
                                                   unsigned short* __restrict__ Wt,
                                                   const int* __restrict__ dst,
                                                   int* __restrict__ bhist,
                                                   int n_edges, int nbuck) {
    if ((int)blockIdx.x < BIN1A_BLOCKS) {
        __shared__ int hist[MAXBUCK];
        const int tid = threadIdx.x;
        const int chunk = (n_edges + BIN1A_BLOCKS - 1) / BIN1A_BLOCKS;
        const int lo = blockIdx.x * chunk;
        const int hi = min(lo + chunk, n_edges);

        for (int i = tid; i < MAXBUCK; i += 256) hist[i] = 0;
        __syncthreads();
        for (int e = lo + tid; e < hi; e += 256)
            atomicAdd(&hist[dst[e] >> BSH], 1);
        __syncthreads();
        for (int i = tid; i < nbuck; i += 256) {
            int c = hist[i];
            if (c) atomicAdd(&bhist[i], c);
        }
    } else {
        int n = blockIdx.x - BIN1A_BLOCKS;   // 0..127
        int k = threadIdx.x;                 // 0..255
        Wt[n * IN_F + k] = f2bf(W[k * OUT_F + n]);
    }
}

// ---------------------------------------------------------------------------
// scanb: single-block exclusive scan over bucket counts -> bstart, gcur.
// ---------------------------------------------------------------------------
__global__ __launch_bounds__(1024) void scanb_kernel(const int* __restrict__ bhist,
                                                     int* __restrict__ bstart,
                                                     int* __restrict__ gcur,
                                                     int* __restrict__ rstart,
                                                     int nbuck, int n_nodes) {
    __shared__ int sh[1024];
    int tid = threadIdx.x;
    int v = (tid < nbuck) ? bhist[tid] : 0;
    sh[tid] = v;
    __syncthreads();
    #pragma unroll
    for (int off = 1; off < 1024; off <<= 1) {
        int t = (tid >= off) ? sh[tid - off] : 0;
        __syncthreads();
        sh[tid] += t;
        __syncthreads();
    }
    int ex = sh[tid] - v;
    if (tid < nbuck) { bstart[tid] = ex; gcur[tid] = ex; }
    if (tid == 1023) {
        bstart[nbuck] = sh[1023];
        rstart[n_nodes] = sh[1023];   // sentinel (== n_edges)
    }
}

// ---------------------------------------------------------------------------
// K3 fused: blocks [0, nbin) = bin1b (two-pass LDS binning into ebuf, 512thr);
// blocks [nbin, nbin+gemm_blocks) = gemm (LDS-staged Wt + MFMA).
// LDS is a 64 KB union (bin1b uses 8 KB of it). bin blocks dispatched first
// so the short bin1b chain starts immediately and hides under gemm.
// ---------------------------------------------------------------------------
__global__ __launch_bounds__(512) void gemm_bin_kernel(
        const float* __restrict__ feat, const unsigned short* __restrict__ Wt,
        unsigned short* __restrict__ h, int n_nodes,
        const int* __restrict__ src, const int* __restrict__ dst,
        int* __restrict__ gcur, unsigned* __restrict__ ebuf,
        int n_edges, int nbuck) {

    __shared__ __align__(16) char smem[65536];

    if ((int)blockIdx.x < BIN1B_BLOCKS) {
        // ---------------- bin1b (512 threads) ----------------
        int* hist  = (int*)smem;
        int* lbase = hist + MAXBUCK;
        const int tid = threadIdx.x;
        const int chunk = (n_edges + BIN1B_BLOCKS - 1) / BIN1B_BLOCKS;
        const int lo = blockIdx.x * chunk;
        const int hi = min(lo + chunk, n_edges);

        for (int i = tid; i < nbuck; i += 512) hist[i] = 0;
        __syncthreads();
        for (int e = lo + tid; e < hi; e += 512)
            atomicAdd(&hist[dst[e] >> BSH], 1);
        __syncthreads();
        for (int i = tid; i < nbuck; i += 512) {
            int c = hist[i];
            lbase[i] = (c > 0) ? atomicAdd(&gcur[i], c) : 0;
            hist[i] = 0;            // reuse as local cursor
        }
        __syncthreads();
        for (int e = lo + tid; e < hi; e += 512) {
            int d = dst[e];
            int bkt = d >> BSH;
            int off = atomicAdd(&hist[bkt], 1);
            ebuf[lbase[bkt] + off] = ((unsigned)src[e] << BSH) | (unsigned)(d & (BNODES - 1));
        }
    } else {
        // ---------------- gemm (8 waves x 16 rows = 128 rows/block) ----------
        unsigned short* Bs = (unsigned short*)smem;   // 64 KB, swizzled

        const int tid  = threadIdx.x;
        const int wave = tid >> 6;
        const int lane = tid & 63;
        const int gb   = blockIdx.x - BIN1B_BLOCKS;
        const int r0   = (gb * 8 + wave) * 16;
        const int lrow = lane & 15;
        const int g    = lane >> 4;          // k-group 0..3
        const int kgrp = g * 8;

        // stage Wt -> LDS (swizzled): 4096 x 16B chunks, 8 per thread
        {
            const f32x4* srcv = reinterpret_cast<const f32x4*>(Wt);
            f32x4* dstv = reinterpret_cast<f32x4*>(Bs);
            #pragma unroll
            for (int i = 0; i < 8; ++i) {
                int c   = tid + i * 512;        // 16B-chunk index 0..4095
                int row = c >> 5;               // 0..127
                int col = c & 31;               // 16B unit within row
                dstv[c] = srcv[row * 32 + (col ^ (row & 7))];
            }
        }

        const int row  = r0 + lrow;
        const int rowc = (row < n_nodes) ? row : (n_nodes - 1);
        const float* arow = feat + (size_t)rowc * IN_F;

        // hoist the wave's entire A footprint: 8 k-steps x 2 f32x4 per lane
        f32x4 a[16];
        #pragma unroll
        for (int k0 = 0; k0 < IN_F / 32; ++k0) {
            a[2 * k0]     = *reinterpret_cast<const f32x4*>(arow + k0 * 32 + kgrp);
            a[2 * k0 + 1] = *reinterpret_cast<const f32x4*>(arow + k0 * 32 + kgrp + 4);
        }
        #pragma unroll
        for (int i = 0; i < 16; ++i)
            asm volatile("" : "+v"(a[i]));

        __syncthreads();   // Bs ready

        f32x4 acc[8];
        #pragma unroll
        for (int n = 0; n < 8; ++n) acc[n] = (f32x4){0.f, 0.f, 0.f, 0.f};

        const bf16x8* bsv = reinterpret_cast<const bf16x8*>(Bs);

        #pragma unroll
        for (int k0 = 0; k0 < IN_F / 32; ++k0) {
            const f32x4 a0 = a[2 * k0];
            const f32x4 a1 = a[2 * k0 + 1];
            bf16x8 afr;
            afr[0] = (short)f2bf(a0[0]);
            afr[1] = (short)f2bf(a0[1]);
            afr[2] = (short)f2bf(a0[2]);
            afr[3] = (short)f2bf(a0[3]);
            afr[4] = (short)f2bf(a1[0]);
            afr[5] = (short)f2bf(a1[1]);
            afr[6] = (short)f2bf(a1[2]);
            afr[7] = (short)f2bf(a1[3]);
            #pragma unroll
            for (int n = 0; n < 8; ++n) {
                const int brow = n * 16 + lrow;
                bf16x8 bfr = bsv[brow * 32 + ((k0 * 4 + g) ^ (brow & 7))];
                acc[n] = __builtin_amdgcn_mfma_f32_16x16x32_bf16(afr, bfr, acc[n], 0, 0, 0);
            }
        }

        const int orow0 = r0 + g * 4;
        #pragma unroll
        for (int n = 0; n < 8; ++n) {
            #pragma unroll
            for (int j = 0; j < 4; ++j) {
                int orow = orow0 + j;
                if (orow < n_nodes)
                    h[(size_t)orow * OUT_F + n * 16 + lrow] = f2bf(acc[n][j]);
            }
        }
    }
}

// ---------------------------------------------------------------------------
// bin2: one block per bucket. Per-node counts from ebuf (LDS), 128-wide scan
// -> rstart + norm, then exact per-node CSR placement. All writes bucket-local.
// ---------------------------------------------------------------------------
__global__ __launch_bounds__(256) void bin2_kernel(const unsigned* __restrict__ ebuf,
                                                   const int* __restrict__ bstart,
                                                   int* __restrict__ rstart,
                                                   float* __restrict__ norm,
                                                   int* __restrict__ eidx,
                                                   int n_nodes) {
    __shared__ int lcnt[BNODES];
    __shared__ int lex[BNODES];
    const int tid = threadIdx.x;
    const int node0 = blockIdx.x << BSH;
    const int e0 = bstart[blockIdx.x];
    const int e1 = bstart[blockIdx.x + 1];

    if (tid < BNODES) lcnt[tid] = 0;
    __syncthreads();
    for (int e = e0 + tid; e < e1; e += 256)
        atomicAdd(&lcnt[ebuf[e] & (BNODES - 1)], 1);
    __syncthreads();

    int own = (tid < BNODES) ? lcnt[tid] : 0;
    if (tid < BNODES) lex[tid] = own;
    __syncthreads();
    #pragma unroll
    for (int off = 1; off < BNODES; off <<= 1) {
        int t = (tid >= off && tid < BNODES) ? lex[tid - off] : 0;
        __syncthreads();
        if (tid < BNODES) lex[tid] += t;
        __syncthreads();
    }
    if (tid < BNODES) {
        int ex = lex[tid] - own;       // exclusive
        lex[tid] = ex;
        int g = node0 + tid;
        if (g <= n_nodes) rstart[g] = e0 + ex;
        if (g < n_nodes) {
            float d = (float)own;
            if (d < 1.0f) d = 1.0f;
            norm[g] = 1.0f / sqrtf(d);
        }
        lcnt[tid] = 0;                 // reuse as cursor
    }
    __syncthreads();

    for (int e = e0 + tid; e < e1; e += 256) {
        unsigned pk = ebuf[e];
        int dl = pk & (BNODES - 1);
        int pos = atomicAdd(&lcnt[dl], 1);
        eidx[e0 + lex[dl] + pos] = (int)(pk >> BSH);
    }
}

// ---------------------------------------------------------------------------
// agg: one wave per dst node. Per 64-edge chunk: eidx + norm[src] loaded
// lane-parallel ONCE (coalesced), distributed via shfl; h-row gathers 4-deep.
// ---------------------------------------------------------------------------
__global__ __launch_bounds__(256) void agg_kernel(const unsigned short* __restrict__ h,
                                                  const int* __restrict__ eidx,
                                                  const int* __restrict__ rstart,
                                                  const float* __restrict__ norm,
                                                  const float* __restrict__ bias,
                                                  float* __restrict__ out,
                                                  int n_nodes) {
    const int wave = threadIdx.x >> 6;
    const int lane = threadIdx.x & 63;
    const int node = blockIdx.x * 4 + wave;
    if (node >= n_nodes) return;

    const int start = rstart[node];
    const int cnt   = rstart[node + 1] - start;

    float a0 = 0.f, a1 = 0.f;
    for (int base = 0; base < cnt; base += 64) {
        const int rem = min(64, cnt - base);
        int   ev = (lane < rem) ? eidx[start + base + lane] : 0;
        float nv = (lane < rem) ? norm[ev] : 0.f;

        int j = 0;
        for (; j + 4 <= rem; j += 4) {
            int s0 = __shfl(ev, j),     s1 = __shfl(ev, j + 1);
            int s2 = __shfl(ev, j + 2), s3 = __shfl(ev, j + 3);
            float n0 = __shfl(nv, j),     n1 = __shfl(nv, j + 1);
            float n2 = __shfl(nv, j + 2), n3 = __shfl(nv, j + 3);
            unsigned v0 = *reinterpret_cast<const unsigned*>(h + (size_t)s0 * OUT_F + lane * 2);
            unsigned v1 = *reinterpret_cast<const unsigned*>(h + (size_t)s1 * OUT_F + lane * 2);
            unsigned v2 = *reinterpret_cast<const unsigned*>(h + (size_t)s2 * OUT_F + lane * 2);
            unsigned v3 = *reinterpret_cast<const unsigned*>(h + (size_t)s3 * OUT_F + lane * 2);
            a0 += bf2f((unsigned short)(v0 & 0xffffu)) * n0;
            a1 += bf2f((unsigned short)(v0 >> 16))     * n0;
            a0 += bf2f((unsigned short)(v1 & 0xffffu)) * n1;
            a1 += bf2f((unsigned short)(v1 >> 16))     * n1;
            a0 += bf2f((unsigned short)(v2 & 0xffffu)) * n2;
            a1 += bf2f((unsigned short)(v2 >> 16))     * n2;
            a0 += bf2f((unsigned short)(v3 & 0xffffu)) * n3;
            a1 += bf2f((unsigned short)(v3 >> 16))     * n3;
        }
        for (; j < rem; ++j) {
            int   s  = __shfl(ev, j);
            float nm = __shfl(nv, j);
            unsigned v = *reinterpret_cast<const unsigned*>(h + (size_t)s * OUT_F + lane * 2);
            a0 += bf2f((unsigned short)(v & 0xffffu)) * nm;
            a1 += bf2f((unsigned short)(v >> 16))     * nm;
        }
    }

    const float nd = norm[node];
    float2 r;
    r.x = a0 * nd + bias[lane * 2];
    r.y = a1 * nd + bias[lane * 2 + 1];
    *reinterpret_cast<float2*>(out + (size_t)node * OUT_F + lane * 2) = r;
}

// ---------------------------------------------------------------------------
extern "C" void kernel_launch(void* const* d_in, const int* in_sizes, int n_in,
                              void* d_out, int out_size, void* d_ws, size_t ws_size,
                              hipStream_t stream) {
    const float* feat   = (const float*)d_in[0];
    const float* weight = (const float*)d_in[1];
    const float* bias   = (const float*)d_in[2];
    const int*   src    = (const int*)d_in[3];
    const int*   dst    = (const int*)d_in[4];
    float* out = (float*)d_out;

    const int n_nodes = in_sizes[0] / IN_F;
    const int n_edges = in_sizes[3];
    const int nbuck   = (n_nodes + BNODES - 1) >> BSH;
    const int gemm_blocks = (n_nodes + 127) / 128;

    char* ws = (char*)d_ws;
    size_t off = 0;
    auto alloc = [&](size_t bytes) {
        char* p = ws + off;
        off += (bytes + 15) & ~(size_t)15;
        return p;
    };
    unsigned short* h  = (unsigned short*)alloc((size_t)n_nodes * OUT_F * 2);
    float* norm        = (float*)alloc((size_t)n_nodes * 4);
    int*   rstart      = (int*)alloc(((size_t)n_nodes + 1) * 4);
    int*   bhist       = (int*)alloc(MAXBUCK * 4);
    int*   bstart      = (int*)alloc((MAXBUCK + 1) * 4);
    int*   gcur        = (int*)alloc(MAXBUCK * 4);
    unsigned short* Wt = (unsigned short*)alloc((size_t)OUT_F * IN_F * 2);
    unsigned* ebuf     = (unsigned*)alloc((size_t)n_edges * 4);
    int*   eidx        = (int*)alloc((size_t)n_edges * 4);

    hipMemsetAsync(bhist, 0, MAXBUCK * sizeof(int), stream);
    // K1: bin1a (blocks 0..255) || wprep (blocks 256..383)
    prep_kernel<<<BIN1A_BLOCKS + OUT_F, 256, 0, stream>>>(weight, Wt, dst, bhist,
                                                          n_edges, nbuck);
    // K2: bucket scan
    scanb_kernel<<<1, 1024, 0, stream>>>(bhist, bstart, gcur, rstart, nbuck, n_nodes);
    // K3: bin1b (blocks 0..255) || gemm (blocks 256..)
    gemm_bin_kernel<<<BIN1B_BLOCKS + gemm_blocks, 512, 0, stream>>>(
        feat, Wt, h, n_nodes, src, dst, gcur, ebuf, n_edges, nbuck);
    // K4: exact CSR
    bin2_kernel<<<nbuck, 256, 0, stream>>>(ebuf, bstart, rstart, norm, eidx, n_nodes);
    // K5: aggregate
    agg_kernel<<<(n_nodes + 3) / 4, 256, 0, stream>>>(h, eidx, rstart, norm, bias, out, n_nodes);
}